// Round 7
// baseline (271.921 us; speedup 1.0000x reference)
//
#include <hip/hip_runtime.h>

// VQ-VAE eval forward, R7: fp16x2-split (3 MFMA products), M=64/wave, K-split 4,
// register-prefetched B-frags from L2-resident precomputed planes; coalesced
// LDS-staged epilogue gather.

#define DIMS 64
#define K_CODES 1024
#define NQ 65536
#define HW 1024
#define TOT 4194304

// ws layout (bytes)
#define WS_NORM   0        // float[1024]
#define WS_FLAGS  4096     // int[1024]
#define WS_LOSS   8192     // float
#define WS_CNT    8256     // int
#define WS_PLANES 16384    // f16[16 tiles][2 planes][8 octets][64 codes][8]  (256 KB)
#define WS_PACK   278528   // u64[65536] (512 KB)

typedef _Float16 f16;
typedef __attribute__((ext_vector_type(8))) _Float16 v8h;  // MFMA A/B frag
typedef __attribute__((ext_vector_type(4))) _Float16 v4h;
typedef __attribute__((ext_vector_type(4))) float f32x4;
typedef unsigned long long u64;

__device__ inline unsigned fenc(float d) {  // monotone float->uint
    union { float f; unsigned u; } v; v.f = d;
    return (v.u & 0x80000000u) ? ~v.u : (v.u | 0x80000000u);
}

#define MFMAH(A_, B_, C_) __builtin_amdgcn_mfma_f32_16x16x32_f16(A_, B_, C_, 0, 0, 0)

// ---------------- Kernel A: fp16 h/l planes + norms + init (64 blocks x 256) ----------
__global__ void vq_prep(const float* __restrict__ emb, char* __restrict__ ws) {
    float* norms = (float*)(ws + WS_NORM);
    int*   flags = (int*)(ws + WS_FLAGS);
    f16*   planes = (f16*)(ws + WS_PLANES);
    u64*   pack  = (u64*)(ws + WS_PACK);

    const int tid = threadIdx.x;
    const int gt  = blockIdx.x * 256 + tid;  // 0..16383 (one float4 of emb each)

    {
        float4 v = ((const float4*)emb)[gt];
        int code = gt >> 4;
        int t    = code >> 6;
        int c    = code & 63;
        int o    = (gt >> 1) & 7;         // octet = d>>3
        int sub  = (gt & 1) * 4;          // d&7 base
        float xs[4] = {v.x, v.y, v.z, v.w};
        v4h hv, lv;
#pragma unroll
        for (int q = 0; q < 4; ++q) {
            f16 h = (f16)xs[q];
            f16 l = (f16)(xs[q] - (float)h);
            hv[q] = h; lv[q] = l;
        }
        f16* base = planes + t * 8192 + (o * 64 + c) * 8 + sub;
        *(v4h*)(base)        = hv;   // h-plane
        *(v4h*)(base + 4096) = lv;   // l-plane
    }
#pragma unroll
    for (int i = 0; i < 4; ++i) pack[gt * 4 + i] = ~0ull;
    if (gt < K_CODES) {
        const float4* row = (const float4*)(emb + gt * DIMS);
        float s = 0.f;
#pragma unroll
        for (int i = 0; i < 16; ++i) {
            float4 v = row[i];
            s += v.x * v.x + v.y * v.y + v.z * v.z + v.w * v.w;
        }
        norms[gt] = s;
        flags[gt] = 0;
    }
    if (gt == 0) { *(float*)(ws + WS_LOSS) = 0.f; *(int*)(ws + WS_CNT) = 0; }
}

// ---------------- Kernel B: MFMA distances + packed argmin (1024 blocks x 256) --------
// blockIdx: ks = bx&3 (256-code quarter), qg = bx>>2 (256-query group).
// Wave = 64 queries (4 row-tiles), scans 256 codes = 16 cs-groups.
__global__ __launch_bounds__(256, 3)
void vq_main(const float* __restrict__ z_e, char* __restrict__ ws) {
    const float* norms = (const float*)(ws + WS_NORM);
    u64* pack = (u64*)(ws + WS_PACK);

    const int tid  = threadIdx.x;
    const int lane = tid & 63;
    const int wid  = tid >> 6;
    const int ks   = blockIdx.x & 3;
    const int qbase = (blockIdx.x >> 2) * 256;
    const int b    = qbase >> 10;
    const int hwb  = qbase & (HW - 1);
    const int col  = lane & 15;
    const int qd   = lane >> 4;

    // Per-lane base into planes (v8h = 8 halfs = 16 B units).
    // frag(t, p, kc, cs) at Pl[t*1024 + p*512 + kc*256 + cs*16]
    const v8h* Pl = ((const v8h*)(ws + WS_PLANES)) + qd * 64 + col;

    // ---- A fragments: 64 rows, fp16 h/l split ----
    v8h ah[4][2], al[4][2];
    {
        const float* zb = z_e + b * (DIMS * HW);
#pragma unroll
        for (int rt = 0; rt < 4; ++rt) {
            int hwq = hwb + wid * 64 + rt * 16 + col;
#pragma unroll
            for (int kc = 0; kc < 2; ++kc) {
                int dbase = kc * 32 + qd * 8;
#pragma unroll
                for (int j = 0; j < 8; ++j) {
                    float x = zb[(dbase + j) * HW + hwq];
                    f16 h = (f16)x;
                    ah[rt][kc][j] = h;
                    al[rt][kc][j] = (f16)(x - (float)h);
                }
            }
        }
    }

    float bestv[4][4];
    int   besti[4][4];
#pragma unroll
    for (int rt = 0; rt < 4; ++rt)
#pragma unroll
        for (int r = 0; r < 4; ++r) { bestv[rt][r] = 3.4e38f; besti[rt][r] = 0; }

    const int t0 = ks * 4;
    // current B-frags + norm (register double-buffer across unrolled loop)
    v8h bh0, bh1, bl0, bl1;
    {
        const v8h* Pt = Pl + t0 * 1024;
        bh0 = Pt[0]; bh1 = Pt[256]; bl0 = Pt[512]; bl1 = Pt[768];
    }
    float nrm = norms[t0 * 64 + col];

#pragma unroll
    for (int it = 0; it < 16; ++it) {
        const int t  = t0 + (it >> 2);
        const int cs = it & 3;
        // prefetch next cs-group
        v8h nh0 = bh0, nh1 = bh1, nl0 = bl0, nl1 = bl1;
        float nn = nrm;
        if (it < 15) {
            const int nt = t0 + ((it + 1) >> 2);
            const int ncs = (it + 1) & 3;
            const v8h* Pn = Pl + nt * 1024 + ncs * 16;
            nh0 = Pn[0]; nh1 = Pn[256]; nl0 = Pn[512]; nl1 = Pn[768];
            nn = norms[nt * 64 + ncs * 16 + col];
        }
        f32x4 acc[4];
#pragma unroll
        for (int rt = 0; rt < 4; ++rt) acc[rt] = (f32x4){0.f, 0.f, 0.f, 0.f};
#pragma unroll
        for (int rt = 0; rt < 4; ++rt) {
            acc[rt] = MFMAH(ah[rt][0], bh0, acc[rt]);   // hh (kc0)
            acc[rt] = MFMAH(ah[rt][0], bl0, acc[rt]);   // hl
            acc[rt] = MFMAH(al[rt][0], bh0, acc[rt]);   // lh
            acc[rt] = MFMAH(ah[rt][1], bh1, acc[rt]);   // hh (kc1)
            acc[rt] = MFMAH(ah[rt][1], bl1, acc[rt]);   // hl
            acc[rt] = MFMAH(al[rt][1], bh1, acc[rt]);   // lh
        }
        int cbase = t * 64 + cs * 16 + col;
#pragma unroll
        for (int rt = 0; rt < 4; ++rt)
#pragma unroll
            for (int r = 0; r < 4; ++r) {
                float d = fmaf(-2.f, acc[rt][r], nrm);
                if (d < bestv[rt][r]) { bestv[rt][r] = d; besti[rt][r] = cbase; }
            }
        bh0 = nh0; bh1 = nh1; bl0 = nl0; bl1 = nl1; nrm = nn;
    }

    // ---- per-row argmin over 16 columns (C/D: row=qd*4+r, col=lane&15) ----
#pragma unroll
    for (int rt = 0; rt < 4; ++rt)
#pragma unroll
    for (int r = 0; r < 4; ++r) {
        float v = bestv[rt][r];
        int   idx = besti[rt][r];
#pragma unroll
        for (int m = 8; m >= 1; m >>= 1) {
            float ov = __shfl_xor(v, m, 64);
            int   oi = __shfl_xor(idx, m, 64);
            if (ov < v || (ov == v && oi < idx)) { v = ov; idx = oi; }
        }
        if (col == 0) {
            int q = qbase + wid * 64 + rt * 16 + qd * 4 + r;
            u64 p = (((u64)fenc(v)) << 32) | (unsigned)idx;
            atomicMin(&pack[q], p);  // device-scope; ties -> smaller idx
        }
    }
}

// ---------------- Kernel C: epilogue (512 blocks x 256) ----------------
__global__ __launch_bounds__(256, 4)
void vq_post(const float* __restrict__ z_e, const float* __restrict__ emb,
             char* __restrict__ ws, float* __restrict__ out) {
    __shared__ float ldsQ[128][65];   // padded: stride-65 reads conflict-free
    __shared__ int   fIdx[128];
    __shared__ float wsum[4];
    __shared__ int   amLast;

    int*   flags   = (int*)(ws + WS_FLAGS);
    float* ws_loss = (float*)(ws + WS_LOSS);
    int*   ws_cnt  = (int*)(ws + WS_CNT);
    const u64* pack = (const u64*)(ws + WS_PACK);

    const int tid  = threadIdx.x;
    const int lane = tid & 63;
    const int wid  = tid >> 6;
    const int qbase = blockIdx.x * 128;

    if (tid < 128) {
        u64 p = pack[qbase + tid];
        int idx = (int)(p & 0xFFFFFFFFu);
        fIdx[tid] = idx;
        out[TOT + 1 + qbase + tid] = (float)idx;
        atomicExch(&flags[idx], 1);  // device-scope
    }
    __syncthreads();

    // Stage winner rows: 16-lane groups load one 256 B row fully coalesced.
    const int rg = tid >> 4;   // 0..15
    const int lo = tid & 15;
#pragma unroll
    for (int i = 0; i < 8; ++i) {
        int q = i * 16 + rg;
        float4 v = ((const float4*)(emb + fIdx[q] * DIMS))[lo];
        ldsQ[q][lo * 4 + 0] = v.x;
        ldsQ[q][lo * 4 + 1] = v.y;
        ldsQ[q][lo * 4 + 2] = v.z;
        ldsQ[q][lo * 4 + 3] = v.w;
    }
    __syncthreads();

    // Coalesced z_q write + mse partial.
    const int q  = tid & 127;
    const int dh = tid >> 7;
    const int n  = qbase + q;
    const int bb = n >> 10;
    const int hw = n & (HW - 1);
    float lsum = 0.f;
#pragma unroll
    for (int it = 0; it < 32; ++it) {
        int d = it * 2 + dh;
        float v = ldsQ[q][d];
        int   o = bb * (DIMS * HW) + d * HW + hw;
        float ze = z_e[o];
        out[o] = v;
        float df = ze - v;
        lsum = fmaf(df, df, lsum);
    }
#pragma unroll
    for (int off = 32; off > 0; off >>= 1) lsum += __shfl_down(lsum, off, 64);
    if (lane == 0) wsum[wid] = lsum;
    __syncthreads();
    if (tid == 0) {
        atomicAdd(ws_loss, wsum[0] + wsum[1] + wsum[2] + wsum[3]);
        __threadfence();
        int prev = atomicAdd(ws_cnt, 1);
        amLast = (prev == (int)gridDim.x - 1);
    }
    __syncthreads();

    if (amLast) {
        __threadfence();
        float c = 0.f;
#pragma unroll
        for (int i = 0; i < 4; ++i)
            c += (float)atomicAdd(&flags[tid + 256 * i], 0);
#pragma unroll
        for (int off = 32; off > 0; off >>= 1) c += __shfl_down(c, off, 64);
        if (lane == 0) wsum[wid] = c;
        __syncthreads();
        if (tid == 0) {
            float used = wsum[0] + wsum[1] + wsum[2] + wsum[3];
            out[TOT + 1 + NQ] = used / (float)K_CODES;
            float L = atomicAdd(ws_loss, 0.f);
            out[TOT] = L / (float)TOT;
        }
    }
}

extern "C" void kernel_launch(void* const* d_in, const int* in_sizes, int n_in,
                              void* d_out, int out_size, void* d_ws, size_t ws_size,
                              hipStream_t stream) {
    const float* z_e = (const float*)d_in[0];
    const float* emb = (const float*)d_in[1];
    float* out = (float*)d_out;
    char* ws = (char*)d_ws;

    vq_prep<<<64, 256, 0, stream>>>(emb, ws);
    vq_main<<<1024, 256, 0, stream>>>(z_e, ws);
    vq_post<<<512, 256, 0, stream>>>(z_e, emb, ws, out);
}